// Round 15
// baseline (347.571 us; speedup 1.0000x reference)
//
#include <hip/hip_runtime.h>
#include <hip/hip_bf16.h>
#include <cstdint>

// ---------------------------------------------------------------------------
// BasicTransformerBlock: LN -> self-attn -> LN -> cross-attn -> LN -> GEGLU FF
// B=2, N=4096, DIM=512, HEADS=8, D_HEAD=64, CTX: M=256, CD=768, FF_INNER=2048
// fp32 residual/LN, bf16 MFMA GEMMs + flash attention.
// R15: attn cross-tile software pipeline -- QK(t+1) MFMAs issued before
//      softmax(t) VALU (two alternating S reg sets, no reg copies);
//      triple-buffered K/V LDS keeps ONE barrier per tile race-free
//      (reads {t,t+1}%3, write (t+2)%3 -- distinct mod 3).
//      GEMM/cross_fused/LN/wtrans = R14 (measured best).
// ---------------------------------------------------------------------------

typedef __bf16 bf16_t;
typedef __bf16 bf16x8 __attribute__((ext_vector_type(8)));
typedef float f32x4 __attribute__((ext_vector_type(4)));
typedef float f32x16 __attribute__((ext_vector_type(16)));

__device__ __forceinline__ bf16_t f2bf(float f) { return (bf16_t)f; }

__device__ __forceinline__ f32x4 mfma16(bf16x8 a, bf16x8 b, f32x4 c) {
  return __builtin_amdgcn_mfma_f32_16x16x32_bf16(a, b, c, 0, 0, 0);
}
__device__ __forceinline__ f32x16 mfma32(bf16x8 a, bf16x8 b, f32x16 c) {
  return __builtin_amdgcn_mfma_f32_32x32x16_bf16(a, b, c, 0, 0, 0);
}

__device__ __forceinline__ float gelu_exact(float x) {
  return 0.5f * x * (1.0f + erff(x * 0.70710678118654752f));
}

// async global->LDS, 16B per lane; lds base wave-uniform, global per-lane.
__device__ __forceinline__ void gload_lds16(const bf16_t* g, bf16_t* lds) {
  __builtin_amdgcn_global_load_lds(
      (const __attribute__((address_space(1))) unsigned int*)g,
      (__attribute__((address_space(3))) unsigned int*)lds, 16, 0, 0);
}

// ---------------------------------------------------------------------------
// LayerNorm: one wave per row of 512 fp32; writes bf16.
// ---------------------------------------------------------------------------
__global__ __launch_bounds__(256) void ln_kernel(const float* __restrict__ in,
                                                 const float* __restrict__ gw,
                                                 const float* __restrict__ bw,
                                                 bf16_t* __restrict__ out) {
  int w = threadIdx.x >> 6, l = threadIdx.x & 63;
  size_t row = (size_t)blockIdx.x * 4 + w;
  const float* p = in + row * 512 + l * 8;
  f32x4 va = *(const f32x4*)p;
  f32x4 vb = *(const f32x4*)(p + 4);
  float xs[8] = {va[0], va[1], va[2], va[3], vb[0], vb[1], vb[2], vb[3]};
  float s = 0.f;
#pragma unroll
  for (int j = 0; j < 8; j++) s += xs[j];
#pragma unroll
  for (int m = 1; m < 64; m <<= 1) s += __shfl_xor(s, m);
  float mu = s * (1.0f / 512.0f);
  float v = 0.f;
#pragma unroll
  for (int j = 0; j < 8; j++) { float d = xs[j] - mu; v += d * d; }
#pragma unroll
  for (int m = 1; m < 64; m <<= 1) v += __shfl_xor(v, m);
  float rstd = rsqrtf(v * (1.0f / 512.0f) + 1e-5f);
  f32x4 g0 = *(const f32x4*)(gw + l * 8);
  f32x4 g1 = *(const f32x4*)(gw + l * 8 + 4);
  f32x4 b0 = *(const f32x4*)(bw + l * 8);
  f32x4 b1 = *(const f32x4*)(bw + l * 8 + 4);
  bf16x8 o;
#pragma unroll
  for (int j = 0; j < 4; j++) o[j] = f2bf((xs[j] - mu) * rstd * g0[j] + b0[j]);
#pragma unroll
  for (int j = 0; j < 4; j++) o[4 + j] = f2bf((xs[4 + j] - mu) * rstd * g1[j] + b1[j]);
  *(bf16x8*)(out + row * 512 + l * 8) = o;
}

// ---------------------------------------------------------------------------
// Fused weight transpose+convert: all 10 weights in one launch.
// ---------------------------------------------------------------------------
struct WJob {
  const float* W;
  bf16_t* Wt;
  int K;
  int N;
  float sc;
  int tile0;
};
struct WJobs {
  WJob j[10];
};

__global__ __launch_bounds__(256) void wtrans_all_kernel(WJobs jobs) {
  __shared__ float t[32][33];
  int bid = blockIdx.x;
  int i = 0;
#pragma unroll
  for (int q = 1; q < 10; q++)
    if (bid >= jobs.j[q].tile0) i = q;
  WJob jb = jobs.j[i];
  int tt = bid - jb.tile0;
  int ktiles = jb.K >> 5;
  int k0 = (tt % ktiles) * 32, n0 = (tt / ktiles) * 32;
#pragma unroll
  for (int s = 0; s < 4; s++) {
    int idx = threadIdx.x + s * 256;
    int kk = idx >> 5, nn = idx & 31;
    t[kk][nn] = jb.W[(size_t)(k0 + kk) * jb.N + n0 + nn];
  }
  __syncthreads();
#pragma unroll
  for (int s = 0; s < 4; s++) {
    int idx = threadIdx.x + s * 256;
    int nn = idx >> 5, kk = idx & 31;
    jb.Wt[(size_t)(n0 + nn) * jb.K + k0 + kk] = f2bf(t[kk][nn] * jb.sc);
  }
}

// fp32 -> bf16 elementwise (n multiple of 1024)
__global__ __launch_bounds__(256) void cvt_kernel(const float* __restrict__ in,
                                                  bf16_t* __restrict__ out) {
  int i = (blockIdx.x * 256 + threadIdx.x) * 4;
  f32x4 v = *(const f32x4*)(in + i);
  out[i + 0] = f2bf(v[0]);
  out[i + 1] = f2bf(v[1]);
  out[i + 2] = f2bf(v[2]);
  out[i + 3] = f2bf(v[3]);
}

// ---------------------------------------------------------------------------
// GEMM (R8 body + R14 XCD swizzle): C[M][N] = A[M][K](bf16) @ Bt[N][K].
// K-step 64 as two 32-col subtiles, double-buffered, global_load_lds staging.
// EPI 0: bf16 out. EPI 1: fp32 out = acc + bias + res.
// EPI 2 (BN=64): GEGLU dual-acc, out bf16 = val * gelu(gate).
// EPI 3: bf16 out, column bits 2<->3 swapped (V^T token permutation).
// ---------------------------------------------------------------------------
template <int BM, int BN, int EPI>
__global__ __launch_bounds__(256) void gemm_kernel(
    const bf16_t* __restrict__ A, const bf16_t* __restrict__ Bt,
    const float* __restrict__ bias, const float* __restrict__ res,
    void* __restrict__ outp, int M, int N, int K, int gateOff, int ldo) {
  constexpr int WR = BM / 2;
  constexpr int WN = BN / 2;
  constexpr int MF = WR / 16;
  constexpr int NF = WN / 16;
  constexpr int ABLK = BM / 64;
  constexpr int BROWS = (EPI == 2) ? 2 * BN : BN;
  constexpr int BBLK = BROWS / 64;
  __shared__ bf16_t Al[2][2][BM][32];    // [buf][khalf][row][col]
  __shared__ bf16_t Bl[2][2][BROWS][32];

  int tid = threadIdx.x;
  int w = tid >> 6, l = tid & 63;
  int wr = w >> 1, wc = w & 1;
  int lg = l >> 4, lc = l & 15;

  // XCD-aware bijective remap (T1): XCD x = lin%8 owns contiguous v-chunk.
  int ntiles = gridDim.y;
  int lin = blockIdx.y * gridDim.x + blockIdx.x;
  int cpx = (gridDim.x * gridDim.y) >> 3;
  int v = (lin & 7) * cpx + (lin >> 3);
  int m0 = (v / ntiles) * BM, n0 = (v % ntiles) * BN;

  f32x4 acc[MF][NF] = {};
  f32x4 acc2[MF][NF] = {};

  int srow = tid >> 2, scol = (tid & 3) * 8;
  const bf16_t* aP[ABLK];
#pragma unroll
  for (int i = 0; i < ABLK; i++)
    aP[i] = A + (size_t)(m0 + i * 64 + srow) * K + scol;
  const bf16_t* bP[BBLK];
  if (EPI == 2) {
    bP[0] = Bt + (size_t)(n0 + srow) * K + scol;
    bP[1] = Bt + (size_t)(n0 + gateOff + srow) * K + scol;
  } else {
#pragma unroll
    for (int i = 0; i < BBLK; i++)
      bP[i] = Bt + (size_t)(n0 + i * 64 + srow) * K + scol;
  }

  auto STAGE = [&](int buf, int k0) {
#pragma unroll
    for (int kh = 0; kh < 2; kh++) {
#pragma unroll
      for (int i = 0; i < ABLK; i++)
        gload_lds16(aP[i] + k0 + kh * 32, &Al[buf][kh][i * 64 + w * 16][0]);
#pragma unroll
      for (int i = 0; i < BBLK; i++)
        gload_lds16(bP[i] + k0 + kh * 32, &Bl[buf][kh][i * 64 + w * 16][0]);
    }
  };

  int nk = K / 64;
  int cur = 0;
  STAGE(0, 0);
  __syncthreads();  // vmcnt(0) drain + barrier: buf0 ready

  for (int t = 0; t < nk; ++t) {
    if (t + 1 < nk) STAGE(cur ^ 1, (t + 1) * 64);  // in flight during compute

#pragma unroll
    for (int kh = 0; kh < 2; kh++) {
      bf16x8 af[MF];
#pragma unroll
      for (int mi = 0; mi < MF; mi++)
        af[mi] = *(const bf16x8*)&Al[cur][kh][wr * WR + mi * 16 + lc][lg * 8];
      bf16x8 bfr[NF];
#pragma unroll
      for (int ni = 0; ni < NF; ni++)
        bfr[ni] = *(const bf16x8*)&Bl[cur][kh][wc * WN + ni * 16 + lc][lg * 8];
#pragma unroll
      for (int mi = 0; mi < MF; mi++)
#pragma unroll
        for (int ni = 0; ni < NF; ni++)
          acc[mi][ni] = mfma16(af[mi], bfr[ni], acc[mi][ni]);
      if (EPI == 2) {
        bf16x8 bg[NF];
#pragma unroll
        for (int ni = 0; ni < NF; ni++)
          bg[ni] =
              *(const bf16x8*)&Bl[cur][kh][BN + wc * WN + ni * 16 + lc][lg * 8];
#pragma unroll
        for (int mi = 0; mi < MF; mi++)
#pragma unroll
          for (int ni = 0; ni < NF; ni++)
            acc2[mi][ni] = mfma16(af[mi], bg[ni], acc2[mi][ni]);
      }
    }
    __syncthreads();  // next tile landed + read-write hazard
    cur ^= 1;
  }

#pragma unroll
  for (int mi = 0; mi < MF; mi++) {
#pragma unroll
    for (int ni = 0; ni < NF; ni++) {
#pragma unroll
      for (int r = 0; r < 4; r++) {
        int row = m0 + wr * WR + mi * 16 + lg * 4 + r;
        int col = n0 + wc * WN + ni * 16 + lc;
        float v2 = acc[mi][ni][r];
        if (EPI == 0) {
          ((bf16_t*)outp)[(size_t)row * ldo + col] = f2bf(v2);
        } else if (EPI == 3) {
          int cs = (col & ~15) | (lc & 3) | ((lc & 4) << 1) | ((lc & 8) >> 1);
          ((bf16_t*)outp)[(size_t)row * ldo + cs] = f2bf(v2);
        } else if (EPI == 1) {
          ((float*)outp)[(size_t)row * ldo + col] =
              v2 + bias[col] + res[(size_t)row * ldo + col];
        } else {
          float g = acc2[mi][ni][r] + bias[col + gateOff];
          float val = v2 + bias[col];
          ((bf16_t*)outp)[(size_t)row * ldo + col] = f2bf(val * gelu_exact(g));
        }
      }
    }
  }
}

// ---------------------------------------------------------------------------
// Fused cross-attn projections (one launch, grid (128,4,2)):
//  z=0:           Q2 proj  C[8192][512] = hb @ q2t  (EPI0)
//  z=1, bx 0..7:  K2 proj  C[512][512]  = ctxb @ k2t (EPI0)
//  z=1, bx 8..15: V2^T     C[512][512]  = v2t @ ctxb^T (EPI3 perm)
//  z=1, bx>=16:   idle.
// ---------------------------------------------------------------------------
__global__ __launch_bounds__(256) void cross_fused_kernel(
    const bf16_t* __restrict__ hb, const bf16_t* __restrict__ q2t,
    bf16_t* __restrict__ qkb, const bf16_t* __restrict__ ctxb,
    const bf16_t* __restrict__ k2t, bf16_t* __restrict__ kb,
    const bf16_t* __restrict__ v2t, bf16_t* __restrict__ vtg2) {
  constexpr int BM = 64, BN = 128;
  constexpr int WR = 32, WN = 64, MF = 2, NF = 4;
  __shared__ bf16_t Al[2][2][BM][32];
  __shared__ bf16_t Bl[2][2][BN][32];

  const bf16_t* A;
  const bf16_t* Bt;
  bf16_t* outp;
  int K, m0;
  bool perm = false;
  if (blockIdx.z == 0) {
    A = hb; Bt = q2t; outp = qkb; K = 512; m0 = blockIdx.x * BM;
  } else {
    int bx = blockIdx.x;
    if (bx >= 16) return;
    K = 768;
    if (bx < 8) {
      A = ctxb; Bt = k2t; outp = kb; m0 = bx * BM;
    } else {
      A = v2t; Bt = ctxb; outp = vtg2; perm = true; m0 = (bx - 8) * BM;
    }
  }
  const int ldo = 512;
  int n0 = blockIdx.y * BN;

  int tid = threadIdx.x;
  int w = tid >> 6, l = tid & 63;
  int wr = w >> 1, wc = w & 1;
  int lg = l >> 4, lc = l & 15;

  f32x4 acc[MF][NF] = {};

  int srow = tid >> 2, scol = (tid & 3) * 8;
  const bf16_t* aP0 = A + (size_t)(m0 + srow) * K + scol;
  const bf16_t* bP0 = Bt + (size_t)(n0 + srow) * K + scol;
  const bf16_t* bP1 = Bt + (size_t)(n0 + 64 + srow) * K + scol;

  auto STAGE = [&](int buf, int k0) {
#pragma unroll
    for (int kh = 0; kh < 2; kh++) {
      gload_lds16(aP0 + k0 + kh * 32, &Al[buf][kh][w * 16][0]);
      gload_lds16(bP0 + k0 + kh * 32, &Bl[buf][kh][w * 16][0]);
      gload_lds16(bP1 + k0 + kh * 32, &Bl[buf][kh][64 + w * 16][0]);
    }
  };

  int nk = K / 64;
  int cur = 0;
  STAGE(0, 0);
  __syncthreads();

  for (int t = 0; t < nk; ++t) {
    if (t + 1 < nk) STAGE(cur ^ 1, (t + 1) * 64);
#pragma unroll
    for (int kh = 0; kh < 2; kh++) {
      bf16x8 af[MF];
#pragma unroll
      for (int mi = 0; mi < MF; mi++)
        af[mi] = *(const bf16x8*)&Al[cur][kh][wr * WR + mi * 16 + lc][lg * 8];
      bf16x8 bfr[NF];
#pragma unroll
      for (int ni = 0; ni < NF; ni++)
        bfr[ni] = *(const bf16x8*)&Bl[cur][kh][wc * WN + ni * 16 + lc][lg * 8];
#pragma unroll
      for (int mi = 0; mi < MF; mi++)
#pragma unroll
        for (int ni = 0; ni < NF; ni++)
          acc[mi][ni] = mfma16(af[mi], bfr[ni], acc[mi][ni]);
    }
    __syncthreads();
    cur ^= 1;
  }

#pragma unroll
  for (int mi = 0; mi < MF; mi++) {
#pragma unroll
    for (int ni = 0; ni < NF; ni++) {
#pragma unroll
      for (int r = 0; r < 4; r++) {
        int row = m0 + wr * WR + mi * 16 + lg * 4 + r;
        int col = n0 + wc * WN + ni * 16 + lc;
        int cs = perm ? ((col & ~15) | (lc & 3) | ((lc & 4) << 1) |
                         ((lc & 8) >> 1))
                      : col;
        outp[(size_t)row * ldo + cs] = f2bf(acc[mi][ni][r]);
      }
    }
  }
}

// ---------------------------------------------------------------------------
// Flash attention on 32x32x16 MFMA. Block = 256 threads (4 waves); each wave
// owns 32 q-rows (q = lane&31); block covers 128 q-rows. KV tiles 64.
// R15: cross-tile pipeline -- QK(t+1) issued BEFORE softmax(t)+PV(t), two
// alternating S reg sets (sA/sB, no copies); TRIPLE-buffered K/V LDS, one
// barrier per tile (interval reads {t,t+1}%3, write (t+2)%3: distinct).
// Regs for tile t+1 loaded a full step ahead. QK^T = mfma32(K,Q) ->
// C[key][q]; softmax lane-local; PV A-frags = lane's own P regs (k-order
// trick); V tokens bit-2/3 pre-swapped (EPI=3); ones-MFMA zacc; scale in Q.
// XCD-aware decode: XCD x owns (head,b) pairs {2x,2x+1} (K/V L2-resident).
// ---------------------------------------------------------------------------
__global__ __launch_bounds__(256) void attn_kernel(
    const bf16_t* __restrict__ Q, int ldq, const bf16_t* __restrict__ Kb,
    int ldk, const bf16_t* __restrict__ Vt, bf16_t* __restrict__ O, int Mkv) {
  __shared__ bf16_t Klds[3][64][72];  // [buf][key][d]
  __shared__ bf16_t Vlds[3][64][72];  // [buf][d][permuted token]

  int lin = blockIdx.x;
  int xcd = lin & 7, slot = lin >> 3;
  int pair = 2 * xcd + (slot >> 5);
  int qt = slot & 31;
  int head = pair & 7, b = pair >> 3;

  int tid = threadIdx.x;
  int w = tid >> 6, l = tid & 63;
  int ql = l & 31, hi = l >> 5;
  int ldv = 2 * Mkv;

  size_t qrow = (size_t)b * 4096 + qt * 128 + w * 32 + ql;
  const bf16_t* qp = Q + qrow * ldq + head * 64 + hi * 8;
  bf16x8 qf[4];
#pragma unroll
  for (int dk = 0; dk < 4; dk++) qf[dk] = *(const bf16x8*)(qp + dk * 16);

  f32x16 o0 = {}, o1 = {};
  f32x16 zacc = {};
  float mrun = -1e30f;
  const f32x16 fzero = {};

  bf16x8 vones;
#pragma unroll
  for (int j = 0; j < 8; j++) vones[j] = f2bf(1.0f);

  int key0 = tid >> 2, dc0 = (tid & 3) * 16;
  const bf16_t* kp = Kb + ((size_t)b * Mkv + key0) * ldk + head * 64 + dc0;
  const bf16_t* vp = Vt + (size_t)(head * 64 + key0) * ldv + b * Mkv + dc0;

  bf16x8 kc0, kc1, vc0, vc1;

  auto LOADCUR = [&]() {
    kc0 = *(const bf16x8*)kp;
    kc1 = *(const bf16x8*)(kp + 8);
    vc0 = *(const bf16x8*)vp;
    vc1 = *(const bf16x8*)(vp + 8);
  };
  auto ADVANCE = [&]() {
    kp += (size_t)64 * ldk;
    vp += 64;
  };
  auto WRITE = [&](int buf) {
    *(bf16x8*)&Klds[buf][key0][dc0] = kc0;
    *(bf16x8*)&Klds[buf][key0][dc0 + 8] = kc1;
    *(bf16x8*)&Vlds[buf][key0][dc0] = vc0;
    *(bf16x8*)&Vlds[buf][key0][dc0 + 8] = vc1;
  };
  auto QK = [&](int buf, f32x16& s0, f32x16& s1) {
    __builtin_amdgcn_s_setprio(1);
#pragma unroll
    for (int dk = 0; dk < 4; dk++) {
      bf16x8 a0 = *(const bf16x8*)&Klds[buf][ql][dk * 16 + hi * 8];
      bf16x8 a1 = *(const bf16x8*)&Klds[buf][32 + ql][dk * 16 + hi * 8];
      s0 = mfma32(a0, qf[dk], s0);
      s1 = mfma32(a1, qf[dk], s1);
    }
    __builtin_amdgcn_s_setprio(0);
  };
  auto SMPV = [&](int t, f32x16& s0, f32x16& s1) {
    float tmax = s0[0];
#pragma unroll
    for (int r = 1; r < 16; r++) tmax = fmaxf(tmax, s0[r]);
#pragma unroll
    for (int r = 0; r < 16; r++) tmax = fmaxf(tmax, s1[r]);
    tmax = fmaxf(tmax, __shfl_xor(tmax, 32));

    if (!__all(tmax <= mrun + 8.0f)) {
      float mnew = fmaxf(mrun, tmax);
      float resc = __builtin_amdgcn_exp2f(mrun - mnew);
      mrun = mnew;
#pragma unroll
      for (int r = 0; r < 16; r++) {
        float f = __shfl(resc, (r & 3) + 8 * (r >> 2) + 4 * hi);
        o0[r] *= f;
        o1[r] *= f;
        zacc[r] *= f;
      }
    }

    bf16x8 pa[4];
#pragma unroll
    for (int m = 0; m < 4; m++) {
#pragma unroll
      for (int j = 0; j < 8; j++) {
        float sv = (m < 2) ? s0[(m & 1) * 8 + j] : s1[(m & 1) * 8 + j];
        pa[m][j] = f2bf(__builtin_amdgcn_exp2f(sv - mrun));
      }
    }

    int vb = t % 3;
    __builtin_amdgcn_s_setprio(1);
#pragma unroll
    for (int m = 0; m < 4; m++) {
      zacc = mfma32(pa[m], vones, zacc);
      bf16x8 vb0 = *(const bf16x8*)&Vlds[vb][ql][m * 16 + hi * 8];
      bf16x8 vb1 = *(const bf16x8*)&Vlds[vb][32 + ql][m * 16 + hi * 8];
      o0 = mfma32(pa[m], vb0, o0);
      o1 = mfma32(pa[m], vb1, o1);
    }
    __builtin_amdgcn_s_setprio(0);
  };

  int nt = Mkv / 64;

  // prologue: tile0 -> buf0; tile1 regs in flight across the barrier
  LOADCUR();
  WRITE(0);
  if (nt > 1) {
    ADVANCE();
    LOADCUR();
  }
  __syncthreads();

  f32x16 sA0 = {}, sA1 = {};
  QK(0, sA0, sA1);

  for (int t = 0; t < nt; t += 2) {
    f32x16 sB0 = {}, sB1 = {};
    if (t + 1 < nt) {
      WRITE((t + 1) % 3);
      if (t + 2 < nt) {
        ADVANCE();
        LOADCUR();
      }
      __syncthreads();
      QK((t + 1) % 3, sB0, sB1);
    }
    SMPV(t, sA0, sA1);
    if (t + 1 >= nt) break;

    sA0 = fzero;
    sA1 = fzero;
    if (t + 2 < nt) {
      WRITE((t + 2) % 3);
      if (t + 3 < nt) {
        ADVANCE();
        LOADCUR();
      }
      __syncthreads();
      QK((t + 2) % 3, sA0, sA1);
    }
    SMPV(t + 1, sB0, sB1);
  }

  size_t ob = ((size_t)b * 4096 + qt * 128 + w * 32) * 512 + head * 64;
#pragma unroll
  for (int r = 0; r < 16; r++) {
    float inv = 1.0f / zacc[r];
    int q = (r & 3) + 8 * (r >> 2) + 4 * hi;
    O[ob + (size_t)q * 512 + ql] = f2bf(o0[r] * inv);
    O[ob + (size_t)q * 512 + 32 + ql] = f2bf(o1[r] * inv);
  }
}

// ---------------------------------------------------------------------------
extern "C" void kernel_launch(void* const* d_in, const int* in_sizes, int n_in,
                              void* d_out, int out_size, void* d_ws,
                              size_t ws_size, hipStream_t stream) {
  const float* x = (const float*)d_in[0];
  const float* ctx = (const float*)d_in[1];
  const float* q1_w = (const float*)d_in[2];
  const float* k1_w = (const float*)d_in[3];
  const float* v1_w = (const float*)d_in[4];
  const float* o1_w = (const float*)d_in[5];
  const float* o1_b = (const float*)d_in[6];
  const float* q2_w = (const float*)d_in[7];
  const float* k2_w = (const float*)d_in[8];
  const float* v2_w = (const float*)d_in[9];
  const float* o2_w = (const float*)d_in[10];
  const float* o2_b = (const float*)d_in[11];
  const float* ff_in_w = (const float*)d_in[12];
  const float* ff_in_b = (const float*)d_in[13];
  const float* ff_out_w = (const float*)d_in[14];
  const float* ff_out_b = (const float*)d_in[15];
  const float* ln1_g = (const float*)d_in[16];
  const float* ln1_b = (const float*)d_in[17];
  const float* ln2_g = (const float*)d_in[18];
  const float* ln2_b = (const float*)d_in[19];
  const float* ln3_g = (const float*)d_in[20];
  const float* ln3_b = (const float*)d_in[21];

  char* ws = (char*)d_ws;
  float* xr = (float*)(ws + 0);                    // 16.78 MB fp32 residual
  bf16_t* hb = (bf16_t*)(ws + 16777216);           // 8.39 MB LN output
  bf16_t* qkb = (bf16_t*)(ws + 25165824);          // 16.78 MB [8192][1024]
  bf16_t* ao = (bf16_t*)(ws + 41943040);           // 8.39 MB
  bf16_t* ffmid = qkb;                             // alias qkb+ao (33.55 MB)
  bf16_t* kb = (bf16_t*)(ws + 50331648);           // 0.52 MB cross K
  bf16_t* vtg2 = (bf16_t*)(ws + 50855936);         // 0.52 MB cross V^T
  bf16_t* ctxb = (bf16_t*)(ws + 51380224);         // 0.79 MB
  bf16_t* wts = (bf16_t*)(ws + 58720256);          // 11.01 MB bf16 weights^T
  bf16_t* vtg = (bf16_t*)(ws + 69730304);          // 8.39 MB V^T [512][8192]

  bf16_t* q1t = wts + 0;        // q1t,k1t adjacent -> fused Q|K weight
  bf16_t* k1t = wts + 262144;
  bf16_t* v1t = wts + 524288;
  bf16_t* o1t = wts + 786432;
  bf16_t* q2t = wts + 1048576;
  bf16_t* k2t = wts + 1310720;
  bf16_t* v2t = wts + 1703936;
  bf16_t* o2t = wts + 2097152;
  bf16_t* ffint = wts + 2359296;
  bf16_t* ffoutt = wts + 4456448;

  const float QS = 0.125f * 1.44269504f;  // attn scale * log2(e) -> into Q

  // fused weight transposes: 10 jobs, one launch
  WJobs jobs;
  auto setj = [&](int i, const float* W, bf16_t* Wt, int K, int N, float sc,
                  int tile0) {
    jobs.j[i] = WJob{W, Wt, K, N, sc, tile0};
  };
  setj(0, q1_w, q1t, 512, 512, QS, 0);
  setj(1, k1_w, k1t, 512, 512, 1.0f, 256);
  setj(2, v1_w, v1t, 512, 512, 1.0f, 512);
  setj(3, o1_w, o1t, 512, 512, 1.0f, 768);
  setj(4, q2_w, q2t, 512, 512, QS, 1024);
  setj(5, k2_w, k2t, 768, 512, 1.0f, 1280);
  setj(6, v2_w, v2t, 768, 512, 1.0f, 1664);
  setj(7, o2_w, o2t, 512, 512, 1.0f, 2048);
  setj(8, ff_in_w, ffint, 512, 4096, 1.0f, 2304);
  setj(9, ff_out_w, ffoutt, 2048, 512, 1.0f, 4352);
  wtrans_all_kernel<<<5376, 256, 0, stream>>>(jobs);
  cvt_kernel<<<384, 256, 0, stream>>>(ctx, ctxb);  // 2*256*768

  // ---- self-attention ----
  ln_kernel<<<2048, 256, 0, stream>>>(x, ln1_g, ln1_b, hb);
  // fused Q|K projection: C[8192][1024] (cols 0..511 Q, 512..1023 K)
  gemm_kernel<128, 128, 0><<<dim3(64, 8), 256, 0, stream>>>(
      hb, q1t, nullptr, nullptr, qkb, 8192, 1024, 512, 0, 1024);
  // V^T = v1t @ hb^T -> vtg[vdim][perm(token)], ldo = 8192 (EPI 3)
  gemm_kernel<64, 128, 3><<<dim3(8, 64), 256, 0, stream>>>(
      v1t, hb, nullptr, nullptr, vtg, 512, 8192, 512, 0, 8192);
  attn_kernel<<<512, 256, 0, stream>>>(qkb, 1024, qkb + 512, 1024, vtg, ao,
                                       4096);
  gemm_kernel<64, 128, 1><<<dim3(128, 4), 256, 0, stream>>>(
      ao, o1t, o1_b, x, xr, 8192, 512, 512, 0, 512);

  // ---- cross-attention ----
  ln_kernel<<<2048, 256, 0, stream>>>(xr, ln2_g, ln2_b, hb);
  // fused: Q2 proj + K2 proj + V2^T in one launch
  cross_fused_kernel<<<dim3(128, 4, 2), 256, 0, stream>>>(
      hb, q2t, qkb, ctxb, k2t, kb, v2t, vtg2);
  attn_kernel<<<512, 256, 0, stream>>>(qkb, 512, kb, 512, vtg2, ao, 256);
  gemm_kernel<64, 128, 1><<<dim3(128, 4), 256, 0, stream>>>(
      ao, o2t, o2_b, xr, xr, 8192, 512, 512, 0, 512);

  // ---- GEGLU FF ----
  ln_kernel<<<2048, 256, 0, stream>>>(xr, ln3_g, ln3_b, hb);
  gemm_kernel<128, 64, 2><<<dim3(64, 32), 256, 0, stream>>>(
      hb, ffint, ff_in_b, nullptr, ffmid, 8192, 2048, 512, 2048, 2048);
  gemm_kernel<64, 128, 1><<<dim3(128, 4), 256, 0, stream>>>(
      ffmid, ffoutt, ff_out_b, xr, (float*)d_out, 8192, 512, 2048, 0, 512);
}

// Round 16
// 278.788 us; speedup vs baseline: 1.2467x; 1.2467x over previous
//
#include <hip/hip_runtime.h>
#include <hip/hip_bf16.h>
#include <cstdint>

// ---------------------------------------------------------------------------
// BasicTransformerBlock: LN -> self-attn -> LN -> cross-attn -> LN -> GEGLU FF
// B=2, N=4096, DIM=512, HEADS=8, D_HEAD=64, CTX: M=256, CD=768, FF_INNER=2048
// fp32 input/output, bf16 MFMA GEMMs + flash attention.
// R16: attn reverted to R14 (measured best: dbuf single-barrier, ones-MFMA
//      zacc; R15's cross-tile pipeline killed occupancy). NEW: bf16 residual
//      stream (saves ~50MB of fp32 round-trips across o1/ln2/o2/ln3/ffout);
//      final d_out stays fp32. GEMM/cross_fused/wtrans = R14.
// ---------------------------------------------------------------------------

typedef __bf16 bf16_t;
typedef __bf16 bf16x8 __attribute__((ext_vector_type(8)));
typedef float f32x4 __attribute__((ext_vector_type(4)));
typedef float f32x16 __attribute__((ext_vector_type(16)));

__device__ __forceinline__ bf16_t f2bf(float f) { return (bf16_t)f; }

__device__ __forceinline__ f32x4 mfma16(bf16x8 a, bf16x8 b, f32x4 c) {
  return __builtin_amdgcn_mfma_f32_16x16x32_bf16(a, b, c, 0, 0, 0);
}
__device__ __forceinline__ f32x16 mfma32(bf16x8 a, bf16x8 b, f32x16 c) {
  return __builtin_amdgcn_mfma_f32_32x32x16_bf16(a, b, c, 0, 0, 0);
}

__device__ __forceinline__ float gelu_exact(float x) {
  return 0.5f * x * (1.0f + erff(x * 0.70710678118654752f));
}

// async global->LDS, 16B per lane; lds base wave-uniform, global per-lane.
__device__ __forceinline__ void gload_lds16(const bf16_t* g, bf16_t* lds) {
  __builtin_amdgcn_global_load_lds(
      (const __attribute__((address_space(1))) unsigned int*)g,
      (__attribute__((address_space(3))) unsigned int*)lds, 16, 0, 0);
}

// ---------------------------------------------------------------------------
// LayerNorm: one wave per row of 512; input fp32 or bf16; writes bf16.
// ---------------------------------------------------------------------------
template <typename T>
__global__ __launch_bounds__(256) void ln_kernel(const T* __restrict__ in,
                                                 const float* __restrict__ gw,
                                                 const float* __restrict__ bw,
                                                 bf16_t* __restrict__ out) {
  int w = threadIdx.x >> 6, l = threadIdx.x & 63;
  size_t row = (size_t)blockIdx.x * 4 + w;
  float xs[8];
  if constexpr (sizeof(T) == 4) {
    const float* p = (const float*)in + row * 512 + l * 8;
    f32x4 va = *(const f32x4*)p;
    f32x4 vb = *(const f32x4*)(p + 4);
#pragma unroll
    for (int j = 0; j < 4; j++) { xs[j] = va[j]; xs[4 + j] = vb[j]; }
  } else {
    const bf16_t* p = (const bf16_t*)in + row * 512 + l * 8;
    bf16x8 v = *(const bf16x8*)p;
#pragma unroll
    for (int j = 0; j < 8; j++) xs[j] = (float)v[j];
  }
  float s = 0.f;
#pragma unroll
  for (int j = 0; j < 8; j++) s += xs[j];
#pragma unroll
  for (int m = 1; m < 64; m <<= 1) s += __shfl_xor(s, m);
  float mu = s * (1.0f / 512.0f);
  float v = 0.f;
#pragma unroll
  for (int j = 0; j < 8; j++) { float d = xs[j] - mu; v += d * d; }
#pragma unroll
  for (int m = 1; m < 64; m <<= 1) v += __shfl_xor(v, m);
  float rstd = rsqrtf(v * (1.0f / 512.0f) + 1e-5f);
  f32x4 g0 = *(const f32x4*)(gw + l * 8);
  f32x4 g1 = *(const f32x4*)(gw + l * 8 + 4);
  f32x4 b0 = *(const f32x4*)(bw + l * 8);
  f32x4 b1 = *(const f32x4*)(bw + l * 8 + 4);
  bf16x8 o;
#pragma unroll
  for (int j = 0; j < 4; j++) o[j] = f2bf((xs[j] - mu) * rstd * g0[j] + b0[j]);
#pragma unroll
  for (int j = 0; j < 4; j++) o[4 + j] = f2bf((xs[4 + j] - mu) * rstd * g1[j] + b1[j]);
  *(bf16x8*)(out + row * 512 + l * 8) = o;
}

// ---------------------------------------------------------------------------
// Fused weight transpose+convert: all 10 weights in one launch.
// ---------------------------------------------------------------------------
struct WJob {
  const float* W;
  bf16_t* Wt;
  int K;
  int N;
  float sc;
  int tile0;
};
struct WJobs {
  WJob j[10];
};

__global__ __launch_bounds__(256) void wtrans_all_kernel(WJobs jobs) {
  __shared__ float t[32][33];
  int bid = blockIdx.x;
  int i = 0;
#pragma unroll
  for (int q = 1; q < 10; q++)
    if (bid >= jobs.j[q].tile0) i = q;
  WJob jb = jobs.j[i];
  int tt = bid - jb.tile0;
  int ktiles = jb.K >> 5;
  int k0 = (tt % ktiles) * 32, n0 = (tt / ktiles) * 32;
#pragma unroll
  for (int s = 0; s < 4; s++) {
    int idx = threadIdx.x + s * 256;
    int kk = idx >> 5, nn = idx & 31;
    t[kk][nn] = jb.W[(size_t)(k0 + kk) * jb.N + n0 + nn];
  }
  __syncthreads();
#pragma unroll
  for (int s = 0; s < 4; s++) {
    int idx = threadIdx.x + s * 256;
    int nn = idx >> 5, kk = idx & 31;
    jb.Wt[(size_t)(n0 + nn) * jb.K + k0 + kk] = f2bf(t[kk][nn] * jb.sc);
  }
}

// fp32 -> bf16 elementwise (n multiple of 1024)
__global__ __launch_bounds__(256) void cvt_kernel(const float* __restrict__ in,
                                                  bf16_t* __restrict__ out) {
  int i = (blockIdx.x * 256 + threadIdx.x) * 4;
  f32x4 v = *(const f32x4*)(in + i);
  out[i + 0] = f2bf(v[0]);
  out[i + 1] = f2bf(v[1]);
  out[i + 2] = f2bf(v[2]);
  out[i + 3] = f2bf(v[3]);
}

// ---------------------------------------------------------------------------
// GEMM (R8 body + R14 XCD swizzle): C[M][N] = A[M][K](bf16) @ Bt[N][K].
// K-step 64 as two 32-col subtiles, double-buffered, global_load_lds staging.
// EPI 0: bf16 out.
// EPI 2 (BN=64): GEGLU dual-acc, out bf16 = val * gelu(gate).
// EPI 3: bf16 out, column bits 2<->3 swapped (V^T token permutation).
// EPI 4: bf16 out = acc + bias + fp32 res.
// EPI 5: bf16 out = acc + bias + bf16 res.
// EPI 6: fp32 out = acc + bias + bf16 res.
// ---------------------------------------------------------------------------
template <int BM, int BN, int EPI>
__global__ __launch_bounds__(256) void gemm_kernel(
    const bf16_t* __restrict__ A, const bf16_t* __restrict__ Bt,
    const float* __restrict__ bias, const void* __restrict__ res,
    void* __restrict__ outp, int M, int N, int K, int gateOff, int ldo) {
  constexpr int WR = BM / 2;
  constexpr int WN = BN / 2;
  constexpr int MF = WR / 16;
  constexpr int NF = WN / 16;
  constexpr int ABLK = BM / 64;
  constexpr int BROWS = (EPI == 2) ? 2 * BN : BN;
  constexpr int BBLK = BROWS / 64;
  __shared__ bf16_t Al[2][2][BM][32];    // [buf][khalf][row][col]
  __shared__ bf16_t Bl[2][2][BROWS][32];

  int tid = threadIdx.x;
  int w = tid >> 6, l = tid & 63;
  int wr = w >> 1, wc = w & 1;
  int lg = l >> 4, lc = l & 15;

  // XCD-aware bijective remap (T1): XCD x = lin%8 owns contiguous v-chunk.
  int ntiles = gridDim.y;
  int lin = blockIdx.y * gridDim.x + blockIdx.x;
  int cpx = (gridDim.x * gridDim.y) >> 3;
  int v = (lin & 7) * cpx + (lin >> 3);
  int m0 = (v / ntiles) * BM, n0 = (v % ntiles) * BN;

  f32x4 acc[MF][NF] = {};
  f32x4 acc2[MF][NF] = {};

  int srow = tid >> 2, scol = (tid & 3) * 8;
  const bf16_t* aP[ABLK];
#pragma unroll
  for (int i = 0; i < ABLK; i++)
    aP[i] = A + (size_t)(m0 + i * 64 + srow) * K + scol;
  const bf16_t* bP[BBLK];
  if (EPI == 2) {
    bP[0] = Bt + (size_t)(n0 + srow) * K + scol;
    bP[1] = Bt + (size_t)(n0 + gateOff + srow) * K + scol;
  } else {
#pragma unroll
    for (int i = 0; i < BBLK; i++)
      bP[i] = Bt + (size_t)(n0 + i * 64 + srow) * K + scol;
  }

  auto STAGE = [&](int buf, int k0) {
#pragma unroll
    for (int kh = 0; kh < 2; kh++) {
#pragma unroll
      for (int i = 0; i < ABLK; i++)
        gload_lds16(aP[i] + k0 + kh * 32, &Al[buf][kh][i * 64 + w * 16][0]);
#pragma unroll
      for (int i = 0; i < BBLK; i++)
        gload_lds16(bP[i] + k0 + kh * 32, &Bl[buf][kh][i * 64 + w * 16][0]);
    }
  };

  int nk = K / 64;
  int cur = 0;
  STAGE(0, 0);
  __syncthreads();  // vmcnt(0) drain + barrier: buf0 ready

  for (int t = 0; t < nk; ++t) {
    if (t + 1 < nk) STAGE(cur ^ 1, (t + 1) * 64);  // in flight during compute

#pragma unroll
    for (int kh = 0; kh < 2; kh++) {
      bf16x8 af[MF];
#pragma unroll
      for (int mi = 0; mi < MF; mi++)
        af[mi] = *(const bf16x8*)&Al[cur][kh][wr * WR + mi * 16 + lc][lg * 8];
      bf16x8 bfr[NF];
#pragma unroll
      for (int ni = 0; ni < NF; ni++)
        bfr[ni] = *(const bf16x8*)&Bl[cur][kh][wc * WN + ni * 16 + lc][lg * 8];
#pragma unroll
      for (int mi = 0; mi < MF; mi++)
#pragma unroll
        for (int ni = 0; ni < NF; ni++)
          acc[mi][ni] = mfma16(af[mi], bfr[ni], acc[mi][ni]);
      if (EPI == 2) {
        bf16x8 bg[NF];
#pragma unroll
        for (int ni = 0; ni < NF; ni++)
          bg[ni] =
              *(const bf16x8*)&Bl[cur][kh][BN + wc * WN + ni * 16 + lc][lg * 8];
#pragma unroll
        for (int mi = 0; mi < MF; mi++)
#pragma unroll
          for (int ni = 0; ni < NF; ni++)
            acc2[mi][ni] = mfma16(af[mi], bg[ni], acc2[mi][ni]);
      }
    }
    __syncthreads();  // next tile landed + read-write hazard
    cur ^= 1;
  }

#pragma unroll
  for (int mi = 0; mi < MF; mi++) {
#pragma unroll
    for (int ni = 0; ni < NF; ni++) {
#pragma unroll
      for (int r = 0; r < 4; r++) {
        int row = m0 + wr * WR + mi * 16 + lg * 4 + r;
        int col = n0 + wc * WN + ni * 16 + lc;
        size_t idx = (size_t)row * ldo + col;
        float v2 = acc[mi][ni][r];
        if (EPI == 0) {
          ((bf16_t*)outp)[idx] = f2bf(v2);
        } else if (EPI == 3) {
          int cs = (col & ~15) | (lc & 3) | ((lc & 4) << 1) | ((lc & 8) >> 1);
          ((bf16_t*)outp)[(size_t)row * ldo + cs] = f2bf(v2);
        } else if (EPI == 4) {
          ((bf16_t*)outp)[idx] =
              f2bf(v2 + bias[col] + ((const float*)res)[idx]);
        } else if (EPI == 5) {
          ((bf16_t*)outp)[idx] =
              f2bf(v2 + bias[col] + (float)((const bf16_t*)res)[idx]);
        } else if (EPI == 6) {
          ((float*)outp)[idx] =
              v2 + bias[col] + (float)((const bf16_t*)res)[idx];
        } else {  // EPI == 2
          float g = acc2[mi][ni][r] + bias[col + gateOff];
          float val = v2 + bias[col];
          ((bf16_t*)outp)[idx] = f2bf(val * gelu_exact(g));
        }
      }
    }
  }
}

// ---------------------------------------------------------------------------
// Fused cross-attn projections (one launch, grid (128,4,2)):
//  z=0:           Q2 proj  C[8192][512] = hb @ q2t  (EPI0)
//  z=1, bx 0..7:  K2 proj  C[512][512]  = ctxb @ k2t (EPI0)
//  z=1, bx 8..15: V2^T     C[512][512]  = v2t @ ctxb^T (EPI3 perm)
//  z=1, bx>=16:   idle.
// ---------------------------------------------------------------------------
__global__ __launch_bounds__(256) void cross_fused_kernel(
    const bf16_t* __restrict__ hb, const bf16_t* __restrict__ q2t,
    bf16_t* __restrict__ qkb, const bf16_t* __restrict__ ctxb,
    const bf16_t* __restrict__ k2t, bf16_t* __restrict__ kb,
    const bf16_t* __restrict__ v2t, bf16_t* __restrict__ vtg2) {
  constexpr int BM = 64, BN = 128;
  constexpr int WR = 32, WN = 64, MF = 2, NF = 4;
  __shared__ bf16_t Al[2][2][BM][32];
  __shared__ bf16_t Bl[2][2][BN][32];

  const bf16_t* A;
  const bf16_t* Bt;
  bf16_t* outp;
  int K, m0;
  bool perm = false;
  if (blockIdx.z == 0) {
    A = hb; Bt = q2t; outp = qkb; K = 512; m0 = blockIdx.x * BM;
  } else {
    int bx = blockIdx.x;
    if (bx >= 16) return;
    K = 768;
    if (bx < 8) {
      A = ctxb; Bt = k2t; outp = kb; m0 = bx * BM;
    } else {
      A = v2t; Bt = ctxb; outp = vtg2; perm = true; m0 = (bx - 8) * BM;
    }
  }
  const int ldo = 512;
  int n0 = blockIdx.y * BN;

  int tid = threadIdx.x;
  int w = tid >> 6, l = tid & 63;
  int wr = w >> 1, wc = w & 1;
  int lg = l >> 4, lc = l & 15;

  f32x4 acc[MF][NF] = {};

  int srow = tid >> 2, scol = (tid & 3) * 8;
  const bf16_t* aP0 = A + (size_t)(m0 + srow) * K + scol;
  const bf16_t* bP0 = Bt + (size_t)(n0 + srow) * K + scol;
  const bf16_t* bP1 = Bt + (size_t)(n0 + 64 + srow) * K + scol;

  auto STAGE = [&](int buf, int k0) {
#pragma unroll
    for (int kh = 0; kh < 2; kh++) {
      gload_lds16(aP0 + k0 + kh * 32, &Al[buf][kh][w * 16][0]);
      gload_lds16(bP0 + k0 + kh * 32, &Bl[buf][kh][w * 16][0]);
      gload_lds16(bP1 + k0 + kh * 32, &Bl[buf][kh][64 + w * 16][0]);
    }
  };

  int nk = K / 64;
  int cur = 0;
  STAGE(0, 0);
  __syncthreads();

  for (int t = 0; t < nk; ++t) {
    if (t + 1 < nk) STAGE(cur ^ 1, (t + 1) * 64);
#pragma unroll
    for (int kh = 0; kh < 2; kh++) {
      bf16x8 af[MF];
#pragma unroll
      for (int mi = 0; mi < MF; mi++)
        af[mi] = *(const bf16x8*)&Al[cur][kh][wr * WR + mi * 16 + lc][lg * 8];
      bf16x8 bfr[NF];
#pragma unroll
      for (int ni = 0; ni < NF; ni++)
        bfr[ni] = *(const bf16x8*)&Bl[cur][kh][wc * WN + ni * 16 + lc][lg * 8];
#pragma unroll
      for (int mi = 0; mi < MF; mi++)
#pragma unroll
        for (int ni = 0; ni < NF; ni++)
          acc[mi][ni] = mfma16(af[mi], bfr[ni], acc[mi][ni]);
    }
    __syncthreads();
    cur ^= 1;
  }

#pragma unroll
  for (int mi = 0; mi < MF; mi++) {
#pragma unroll
    for (int ni = 0; ni < NF; ni++) {
#pragma unroll
      for (int r = 0; r < 4; r++) {
        int row = m0 + wr * WR + mi * 16 + lg * 4 + r;
        int col = n0 + wc * WN + ni * 16 + lc;
        int cs = perm ? ((col & ~15) | (lc & 3) | ((lc & 4) << 1) |
                         ((lc & 8) >> 1))
                      : col;
        outp[(size_t)row * ldo + cs] = f2bf(acc[mi][ni][r]);
      }
    }
  }
}

// ---------------------------------------------------------------------------
// Flash attention on 32x32x16 MFMA (R14 version -- measured best). Block =
// 256 threads (4 waves); each wave owns 32 q-rows (q = lane&31); block
// covers 128 q-rows. KV tiles 64. DOUBLE-BUFFERED K/V LDS, ONE barrier per
// tile; loads issued a full tile ahead. QK^T = mfma32(K, Q) -> C[key][q];
// softmax lane-local; PV A-frags are the lane's own P regs (k-order trick);
// V tokens bit-2/3 pre-swapped (EPI=3); ones-MFMA zacc; scale folded into Q.
// XCD-aware decode: XCD x owns (head,b) pairs {2x,2x+1} (K/V L2-resident).
// ---------------------------------------------------------------------------
__global__ __launch_bounds__(256) void attn_kernel(
    const bf16_t* __restrict__ Q, int ldq, const bf16_t* __restrict__ Kb,
    int ldk, const bf16_t* __restrict__ Vt, bf16_t* __restrict__ O, int Mkv) {
  __shared__ bf16_t Klds[2][64][72];  // [buf][key][d]
  __shared__ bf16_t Vlds[2][64][72];  // [buf][d][permuted token]

  int lin = blockIdx.x;
  int xcd = lin & 7, slot = lin >> 3;
  int pair = 2 * xcd + (slot >> 5);
  int qt = slot & 31;
  int head = pair & 7, b = pair >> 3;

  int tid = threadIdx.x;
  int w = tid >> 6, l = tid & 63;
  int ql = l & 31, hi = l >> 5;
  int ldv = 2 * Mkv;

  size_t qrow = (size_t)b * 4096 + qt * 128 + w * 32 + ql;
  const bf16_t* qp = Q + qrow * ldq + head * 64 + hi * 8;
  bf16x8 qf[4];
#pragma unroll
  for (int dk = 0; dk < 4; dk++) qf[dk] = *(const bf16x8*)(qp + dk * 16);

  f32x16 o0 = {}, o1 = {};
  f32x16 zacc = {};
  float mrun = -1e30f;

  bf16x8 vones;
#pragma unroll
  for (int j = 0; j < 8; j++) vones[j] = f2bf(1.0f);

  int key0 = tid >> 2, dc0 = (tid & 3) * 16;
  const bf16_t* kp = Kb + ((size_t)b * Mkv + key0) * ldk + head * 64 + dc0;
  const bf16_t* vp = Vt + (size_t)(head * 64 + key0) * ldv + b * Mkv + dc0;

  int nt = Mkv / 64;

  // prologue: tile 0 -> buf0 directly; tile 1 loads issued before barrier
  bf16x8 kc0 = *(const bf16x8*)kp, kc1 = *(const bf16x8*)(kp + 8);
  bf16x8 vc0 = *(const bf16x8*)vp, vc1 = *(const bf16x8*)(vp + 8);
  *(bf16x8*)&Klds[0][key0][dc0] = kc0;
  *(bf16x8*)&Klds[0][key0][dc0 + 8] = kc1;
  *(bf16x8*)&Vlds[0][key0][dc0] = vc0;
  *(bf16x8*)&Vlds[0][key0][dc0 + 8] = vc1;
  if (nt > 1) {
    kp += (size_t)64 * ldk;
    vp += 64;
    kc0 = *(const bf16x8*)kp;
    kc1 = *(const bf16x8*)(kp + 8);
    vc0 = *(const bf16x8*)vp;
    vc1 = *(const bf16x8*)(vp + 8);
  }
  __syncthreads();

  for (int t = 0; t < nt; ++t) {
    int cur = t & 1;

    // S^T = K Q^T from Klds[cur]
    f32x16 s0 = {}, s1 = {};
    __builtin_amdgcn_s_setprio(1);
#pragma unroll
    for (int dk = 0; dk < 4; dk++) {
      bf16x8 a0 = *(const bf16x8*)&Klds[cur][ql][dk * 16 + hi * 8];
      bf16x8 a1 = *(const bf16x8*)&Klds[cur][32 + ql][dk * 16 + hi * 8];
      s0 = mfma32(a0, qf[dk], s0);
      s1 = mfma32(a1, qf[dk], s1);
    }
    __builtin_amdgcn_s_setprio(0);

    float tmax = s0[0];
#pragma unroll
    for (int r = 1; r < 16; r++) tmax = fmaxf(tmax, s0[r]);
#pragma unroll
    for (int r = 0; r < 16; r++) tmax = fmaxf(tmax, s1[r]);
    tmax = fmaxf(tmax, __shfl_xor(tmax, 32));

    if (!__all(tmax <= mrun + 8.0f)) {
      float mnew = fmaxf(mrun, tmax);
      float resc = __builtin_amdgcn_exp2f(mrun - mnew);
      mrun = mnew;
#pragma unroll
      for (int r = 0; r < 16; r++) {
        float f = __shfl(resc, (r & 3) + 8 * (r >> 2) + 4 * hi);
        o0[r] *= f;
        o1[r] *= f;
        zacc[r] *= f;
      }
    }

    bf16x8 pa[4];
#pragma unroll
    for (int m = 0; m < 4; m++) {
#pragma unroll
      for (int j = 0; j < 8; j++) {
        float sv = (m < 2) ? s0[(m & 1) * 8 + j] : s1[(m & 1) * 8 + j];
        pa[m][j] = f2bf(__builtin_amdgcn_exp2f(sv - mrun));
      }
    }

    __builtin_amdgcn_s_setprio(1);
#pragma unroll
    for (int m = 0; m < 4; m++) {
      zacc = mfma32(pa[m], vones, zacc);
      bf16x8 vb0 = *(const bf16x8*)&Vlds[cur][ql][m * 16 + hi * 8];
      bf16x8 vb1 = *(const bf16x8*)&Vlds[cur][32 + ql][m * 16 + hi * 8];
      o0 = mfma32(pa[m], vb0, o0);
      o1 = mfma32(pa[m], vb1, o1);
    }
    __builtin_amdgcn_s_setprio(0);

    // write tile t+1 (loaded a full tile ago) into the other buffer, then
    // issue tile t+2 loads; one barrier makes the write visible for t+1.
    if (t + 1 < nt) {
      *(bf16x8*)&Klds[cur ^ 1][key0][dc0] = kc0;
      *(bf16x8*)&Klds[cur ^ 1][key0][dc0 + 8] = kc1;
      *(bf16x8*)&Vlds[cur ^ 1][key0][dc0] = vc0;
      *(bf16x8*)&Vlds[cur ^ 1][key0][dc0 + 8] = vc1;
      if (t + 2 < nt) {
        kp += (size_t)64 * ldk;
        vp += 64;
        kc0 = *(const bf16x8*)kp;
        kc1 = *(const bf16x8*)(kp + 8);
        vc0 = *(const bf16x8*)vp;
        vc1 = *(const bf16x8*)(vp + 8);
      }
      __syncthreads();
    }
  }

  size_t ob = ((size_t)b * 4096 + qt * 128 + w * 32) * 512 + head * 64;
#pragma unroll
  for (int r = 0; r < 16; r++) {
    float inv = 1.0f / zacc[r];
    int q = (r & 3) + 8 * (r >> 2) + 4 * hi;
    O[ob + (size_t)q * 512 + ql] = f2bf(o0[r] * inv);
    O[ob + (size_t)q * 512 + 32 + ql] = f2bf(o1[r] * inv);
  }
}

// ---------------------------------------------------------------------------
extern "C" void kernel_launch(void* const* d_in, const int* in_sizes, int n_in,
                              void* d_out, int out_size, void* d_ws,
                              size_t ws_size, hipStream_t stream) {
  const float* x = (const float*)d_in[0];
  const float* ctx = (const float*)d_in[1];
  const float* q1_w = (const float*)d_in[2];
  const float* k1_w = (const float*)d_in[3];
  const float* v1_w = (const float*)d_in[4];
  const float* o1_w = (const float*)d_in[5];
  const float* o1_b = (const float*)d_in[6];
  const float* q2_w = (const float*)d_in[7];
  const float* k2_w = (const float*)d_in[8];
  const float* v2_w = (const float*)d_in[9];
  const float* o2_w = (const float*)d_in[10];
  const float* o2_b = (const float*)d_in[11];
  const float* ff_in_w = (const float*)d_in[12];
  const float* ff_in_b = (const float*)d_in[13];
  const float* ff_out_w = (const float*)d_in[14];
  const float* ff_out_b = (const float*)d_in[15];
  const float* ln1_g = (const float*)d_in[16];
  const float* ln1_b = (const float*)d_in[17];
  const float* ln2_g = (const float*)d_in[18];
  const float* ln2_b = (const float*)d_in[19];
  const float* ln3_g = (const float*)d_in[20];
  const float* ln3_b = (const float*)d_in[21];

  char* ws = (char*)d_ws;
  bf16_t* xrb1 = (bf16_t*)(ws + 0);                // 8.39 MB bf16 residual 1
  bf16_t* xrb2 = (bf16_t*)(ws + 8388608);          // 8.39 MB bf16 residual 2
  bf16_t* hb = (bf16_t*)(ws + 16777216);           // 8.39 MB LN output
  bf16_t* qkb = (bf16_t*)(ws + 25165824);          // 16.78 MB [8192][1024]
  bf16_t* ao = (bf16_t*)(ws + 41943040);           // 8.39 MB
  bf16_t* ffmid = qkb;                             // alias qkb+ao (33.55 MB)
  bf16_t* kb = (bf16_t*)(ws + 50331648);           // 0.52 MB cross K
  bf16_t* vtg2 = (bf16_t*)(ws + 50855936);         // 0.52 MB cross V^T
  bf16_t* ctxb = (bf16_t*)(ws + 51380224);         // 0.79 MB
  bf16_t* wts = (bf16_t*)(ws + 58720256);          // 11.01 MB bf16 weights^T
  bf16_t* vtg = (bf16_t*)(ws + 69730304);          // 8.39 MB V^T [512][8192]

  bf16_t* q1t = wts + 0;        // q1t,k1t adjacent -> fused Q|K weight
  bf16_t* k1t = wts + 262144;
  bf16_t* v1t = wts + 524288;
  bf16_t* o1t = wts + 786432;
  bf16_t* q2t = wts + 1048576;
  bf16_t* k2t = wts + 1310720;
  bf16_t* v2t = wts + 1703936;
  bf16_t* o2t = wts + 2097152;
  bf16_t* ffint = wts + 2359296;
  bf16_t* ffoutt = wts + 4456448;

  const float QS = 0.125f * 1.44269504f;  // attn scale * log2(e) -> into Q

  // fused weight transposes: 10 jobs, one launch
  WJobs jobs;
  auto setj = [&](int i, const float* W, bf16_t* Wt, int K, int N, float sc,
                  int tile0) {
    jobs.j[i] = WJob{W, Wt, K, N, sc, tile0};
  };
  setj(0, q1_w, q1t, 512, 512, QS, 0);
  setj(1, k1_w, k1t, 512, 512, 1.0f, 256);
  setj(2, v1_w, v1t, 512, 512, 1.0f, 512);
  setj(3, o1_w, o1t, 512, 512, 1.0f, 768);
  setj(4, q2_w, q2t, 512, 512, QS, 1024);
  setj(5, k2_w, k2t, 768, 512, 1.0f, 1280);
  setj(6, v2_w, v2t, 768, 512, 1.0f, 1664);
  setj(7, o2_w, o2t, 512, 512, 1.0f, 2048);
  setj(8, ff_in_w, ffint, 512, 4096, 1.0f, 2304);
  setj(9, ff_out_w, ffoutt, 2048, 512, 1.0f, 4352);
  wtrans_all_kernel<<<5376, 256, 0, stream>>>(jobs);
  cvt_kernel<<<384, 256, 0, stream>>>(ctx, ctxb);  // 2*256*768

  // ---- self-attention ----
  ln_kernel<float><<<2048, 256, 0, stream>>>(x, ln1_g, ln1_b, hb);
  // fused Q|K projection: C[8192][1024] (cols 0..511 Q, 512..1023 K)
  gemm_kernel<128, 128, 0><<<dim3(64, 8), 256, 0, stream>>>(
      hb, q1t, nullptr, nullptr, qkb, 8192, 1024, 512, 0, 1024);
  // V^T = v1t @ hb^T -> vtg[vdim][perm(token)], ldo = 8192 (EPI 3)
  gemm_kernel<64, 128, 3><<<dim3(8, 64), 256, 0, stream>>>(
      v1t, hb, nullptr, nullptr, vtg, 512, 8192, 512, 0, 8192);
  attn_kernel<<<512, 256, 0, stream>>>(qkb, 1024, qkb + 512, 1024, vtg, ao,
                                       4096);
  // O1 proj: bf16 residual = acc + bias + fp32 x (EPI 4)
  gemm_kernel<64, 128, 4><<<dim3(128, 4), 256, 0, stream>>>(
      ao, o1t, o1_b, x, xrb1, 8192, 512, 512, 0, 512);

  // ---- cross-attention ----
  ln_kernel<bf16_t><<<2048, 256, 0, stream>>>(xrb1, ln2_g, ln2_b, hb);
  // fused: Q2 proj + K2 proj + V2^T in one launch
  cross_fused_kernel<<<dim3(128, 4, 2), 256, 0, stream>>>(
      hb, q2t, qkb, ctxb, k2t, kb, v2t, vtg2);
  attn_kernel<<<512, 256, 0, stream>>>(qkb, 512, kb, 512, vtg2, ao, 256);
  // O2 proj: bf16 residual = acc + bias + bf16 xrb1 (EPI 5)
  gemm_kernel<64, 128, 5><<<dim3(128, 4), 256, 0, stream>>>(
      ao, o2t, o2_b, xrb1, xrb2, 8192, 512, 512, 0, 512);

  // ---- GEGLU FF ----
  ln_kernel<bf16_t><<<2048, 256, 0, stream>>>(xrb2, ln3_g, ln3_b, hb);
  gemm_kernel<128, 64, 2><<<dim3(64, 32), 256, 0, stream>>>(
      hb, ffint, ff_in_b, nullptr, ffmid, 8192, 2048, 512, 2048, 2048);
  // FF out: fp32 d_out = acc + bias + bf16 xrb2 (EPI 6)
  gemm_kernel<64, 128, 6><<<dim3(128, 4), 256, 0, stream>>>(
      ffmid, ffoutt, ff_out_b, xrb2, (float*)d_out, 8192, 512, 2048, 0, 512);
}